// Round 4
// baseline (529.590 us; speedup 1.0000x reference)
//
#include <hip/hip_runtime.h>
#include <hip/hip_bf16.h>
#include <cstdint>
#include <cstddef>

typedef unsigned short u16;
typedef unsigned int u32;
typedef __attribute__((ext_vector_type(8))) short short8;
typedef __attribute__((ext_vector_type(16))) float floatx16;

#define DD 1024
#define NE 8

// 16-byte async global->LDS copy (gfx950). LDS dest must be wave-uniform base + lane*16;
// global source address is per-lane (gather OK).
#define GLOAD_LDS16(G, L)                                               \
  __builtin_amdgcn_global_load_lds(                                     \
      (const __attribute__((address_space(1))) void*)(G),               \
      (__attribute__((address_space(3))) void*)(L), 16, 0, 0)

__device__ __forceinline__ u16 f2bf(float f) {
  union { __hip_bfloat16 h; u16 u; } cv;
  cv.h = __float2bfloat16(f);
  return cv.u;
}

__device__ __forceinline__ float2 bf2f2(u32 u) {
  union { u32 v; float f; } lo, hi;
  lo.v = u << 16; hi.v = u & 0xffff0000u;
  float2 r; r.x = lo.f; r.y = hi.f; return r;
}

// ---------------- router: fp32 logits, top-2, softmax weights; emits x bf16; counts/expert ----------------
__global__ __launch_bounds__(256) void router_kernel(
    const float* __restrict__ x, const float* __restrict__ rw,
    const float* __restrict__ rb, int2* __restrict__ experts,
    float2* __restrict__ wts, u16* __restrict__ xbf,
    int* __restrict__ counts, int T) {
  __shared__ int lc[NE];
  if (threadIdx.x < NE) lc[threadIdx.x] = 0;
  __syncthreads();
  const int wave = threadIdx.x >> 6;
  const int lane = threadIdx.x & 63;
  const int t = blockIdx.x * 4 + wave;
  if (t < T) {
    const float* xr = x + (size_t)t * DD;
    float acc[NE] = {0.f, 0.f, 0.f, 0.f, 0.f, 0.f, 0.f, 0.f};
#pragma unroll
    for (int i = 0; i < 16; i++) {
      const int idx = lane + i * 64;
      const float xv = xr[idx];
      xbf[(size_t)t * DD + idx] = f2bf(xv);
      const float4* r4 = (const float4*)(rw + (size_t)idx * NE);
      float4 a = r4[0], b = r4[1];
      acc[0] += xv * a.x; acc[1] += xv * a.y; acc[2] += xv * a.z; acc[3] += xv * a.w;
      acc[4] += xv * b.x; acc[5] += xv * b.y; acc[6] += xv * b.z; acc[7] += xv * b.w;
    }
#pragma unroll
    for (int s = 1; s < 64; s <<= 1)
#pragma unroll
      for (int e = 0; e < NE; e++)
        acc[e] += __shfl_xor(acc[e], s);
    if (lane == 0) {
      float lg[NE];
#pragma unroll
      for (int e = 0; e < NE; e++) lg[e] = acc[e] + rb[e];
      float l0 = lg[0]; int i0 = 0;
#pragma unroll
      for (int e = 1; e < NE; e++) if (lg[e] > l0) { l0 = lg[e]; i0 = e; }
      float l1 = -3.4e38f; int i1 = 0;
#pragma unroll
      for (int e = 0; e < NE; e++) {
        if (e == i0) continue;
        if (lg[e] > l1) { l1 = lg[e]; i1 = e; }
      }
      const float w0 = 1.f / (1.f + expf(l1 - l0));
      experts[t] = make_int2(i0, i1);
      wts[t] = make_float2(w0, 1.f - w0);
      atomicAdd(&lc[i0], 1);
      atomicAdd(&lc[i1], 1);
    }
  }
  __syncthreads();
  if (threadIdx.x < NE && lc[threadIdx.x] > 0)
    atomicAdd(&counts[threadIdx.x], lc[threadIdx.x]);
}

// ---------------- scatter: compact expert groups + inverse map; offsets computed inline ----------------
__global__ __launch_bounds__(256) void scatter_kernel(
    const int2* __restrict__ experts, const int* __restrict__ counts,
    int* __restrict__ cursors, int* __restrict__ tok_id,
    int2* __restrict__ slots, int T) {
  __shared__ int lc[NE], lb[NE];
  if (threadIdx.x < NE) lc[threadIdx.x] = 0;
  __syncthreads();
  const int t = blockIdx.x * 256 + threadIdx.x;
  int2 e = make_int2(0, 0);
  int p0 = 0, p1 = 0;
  if (t < T) {
    e = experts[t];
    p0 = atomicAdd(&lc[e.x], 1);
    p1 = atomicAdd(&lc[e.y], 1);
  }
  __syncthreads();
  if (threadIdx.x < NE) lb[threadIdx.x] = atomicAdd(&cursors[threadIdx.x], lc[threadIdx.x]);
  __syncthreads();
  if (t < T) {
    int offs[NE];
    int s = 0;
#pragma unroll
    for (int i = 0; i < NE; i++) { offs[i] = s; s += counts[i]; }
    const int s0 = offs[e.x] + lb[e.x] + p0;
    const int s1 = offs[e.y] + lb[e.y] + p1;
    tok_id[s0] = t;
    tok_id[s1] = t;
    slots[t] = make_int2(s0, s1);
  }
}

__global__ void offsets_kernel(const int* __restrict__ counts, int* __restrict__ offsets) {
  int s = 0;
  for (int e = 0; e < NE; e++) { offsets[e] = s; s += counts[e]; }
}

// ---------------- weight transpose + fp32->bf16 convert ----------------
// Wgu: [e][nc][k], nc = ((n>>3)<<4) | (which<<3) | (n&7); Wd: [e][n][k]
__global__ __launch_bounds__(256) void convert_kernel(
    const float* __restrict__ wg, const float* __restrict__ wu,
    const float* __restrict__ wd, u16* __restrict__ Wgu, u16* __restrict__ Wd) {
  const int z = blockIdx.z;        // mat*8 + e
  const int mat = z >> 3;
  const int e = z & 7;
  const float* src = (mat == 0 ? wg : (mat == 1 ? wu : wd)) + (size_t)e * DD * DD;
  __shared__ float tile[64][65];
  const int k0 = blockIdx.y * 64, n0 = blockIdx.x * 64;
  const int tx = threadIdx.x & 63, ty = threadIdx.x >> 6;
#pragma unroll
  for (int i = 0; i < 16; i++) {
    const int kk = i * 4 + ty;
    tile[kk][tx] = src[(size_t)(k0 + kk) * DD + n0 + tx];
  }
  __syncthreads();
#pragma unroll
  for (int i = 0; i < 16; i++) {
    const int nn = i * 4 + ty;
    const int n = n0 + nn;
    const u16 h = f2bf(tile[tx][nn]);   // = src[k0+tx][n]
    if (mat == 2) {
      Wd[((size_t)e * DD + n) * DD + k0 + tx] = h;
    } else {
      const int nc = ((n >> 3) << 4) | (mat << 3) | (n & 7);
      Wgu[((size_t)e * 2048 + nc) * DD + k0 + tx] = h;
    }
  }
}

// ---------------- grouped GEMM 1: H = silu(x@Wg)*(x@Wu), 32x32x16 MFMA, BK=64, swizzled ----------------
__global__ __launch_bounds__(256) void gateup_kernel(
    const u16* __restrict__ xbf, const u16* __restrict__ Wgu,
    const int* __restrict__ tok_id, const int* __restrict__ offsets,
    const int* __restrict__ counts, u16* __restrict__ H) {
  const int e = blockIdx.z;
  const int cnt = counts[e];
  const int m0 = blockIdx.y * 128;
  if (m0 >= cnt) return;
  const int off = offsets[e];
  const int n0 = blockIdx.x * 128;

  __shared__ u16 As[128 * 64];
  __shared__ u16 Bs[128 * 64];

  const int t = threadIdx.x;
  const int lane = t & 63;
  const int wave = t >> 6;
  const int wm = (wave >> 1) * 64;
  const int wn = (wave & 1) * 64;
  const int r32 = lane & 31;
  const int half = lane >> 5;

  // DMA mapping: issue i covers rows i*32 + (t>>3); lane supplies chunk position t&7,
  // whose LOGICAL k-chunk is (t&7) ^ (row&7)  (XOR swizzle; dest stays lane-linear).
  const int drow = t >> 3;
  const int dpos = t & 7;
  const u16* srcA[4];
  const u16* srcB[4];
  const u16* bbase = Wgu + ((size_t)e * 2048 + n0) * DD;
#pragma unroll
  for (int i = 0; i < 4; i++) {
    const int row = drow + i * 32;
    int r = m0 + row; if (r > cnt - 1) r = cnt - 1;
    const int tok = tok_id[off + r];
    const int ka = (dpos ^ (row & 7)) * 8;
    srcA[i] = xbf + (size_t)tok * DD + ka;
    srcB[i] = bbase + (size_t)row * DD + ka;
  }

  floatx16 acc[2][2];
#pragma unroll
  for (int i = 0; i < 2; i++)
#pragma unroll
    for (int j = 0; j < 2; j++)
      acc[i][j] = (floatx16)(0.f);

#pragma unroll 1
  for (int k0 = 0; k0 < DD; k0 += 64) {
    __syncthreads();
#pragma unroll
    for (int i = 0; i < 4; i++) {
      GLOAD_LDS16(srcA[i] + k0, &As[t * 8 + i * 2048]);
      GLOAD_LDS16(srcB[i] + k0, &Bs[t * 8 + i * 2048]);
    }
    __syncthreads();
#pragma unroll
    for (int s = 0; s < 4; s++) {
      const int kc = ((2 * s + half) ^ (r32 & 7)) * 8;   // swizzled 8-elem chunk for k-step s
      short8 a[2], b[2];
#pragma unroll
      for (int i = 0; i < 2; i++)
        a[i] = *(const short8*)&As[(wm + i * 32 + r32) * 64 + kc];
#pragma unroll
      for (int j = 0; j < 2; j++)
        b[j] = *(const short8*)&Bs[(wn + j * 32 + r32) * 64 + kc];
#pragma unroll
      for (int i = 0; i < 2; i++)
#pragma unroll
        for (int j = 0; j < 2; j++)
          acc[i][j] = __builtin_amdgcn_mfma_f32_32x32x16_bf16(a[i], b[j], acc[i][j], 0, 0, 0);
    }
  }

  // epilogue: C/D row=(reg&3)+8*(reg>>2)+4*half, col=r32. gate at nc bit3==0 (== lane bit3).
  // pair gate/up via shfl_xor 8 (col^8 <=> lane^8), silu, write bf16 H.
#pragma unroll
  for (int i = 0; i < 2; i++) {
#pragma unroll
    for (int j = 0; j < 2; j++) {
      const int nc = n0 + wn + j * 32 + r32;
      const int ng = ((nc >> 4) << 3) | (nc & 7);
#pragma unroll
      for (int reg = 0; reg < 16; reg++) {
        const float v = acc[i][j][reg];
        const float pv = __shfl_xor(v, 8);
        const float g = (lane & 8) ? pv : v;
        const float u = (lane & 8) ? v : pv;
        const float hv = g * u / (1.f + __expf(-g));
        const int m = m0 + wm + i * 32 + (reg & 3) + 8 * (reg >> 2) + 4 * half;
        if (!(lane & 8) && m < cnt)
          H[(size_t)(off + m) * DD + ng] = f2bf(hv);
      }
    }
  }
}

// ---------------- grouped GEMM 2: Y[slot] = H[slot] @ Wd (32x32x16, bf16 stores, no atomics) ----------------
__global__ __launch_bounds__(256) void down_kernel(
    const u16* __restrict__ H, const u16* __restrict__ Wd,
    const int* __restrict__ counts, const int* __restrict__ offsets,
    u16* __restrict__ Y, int TK2) {
  const int e = blockIdx.z;
  const int cnt = counts[e];
  const int m0 = blockIdx.y * 128;
  if (m0 >= cnt) return;
  const int off = offsets[e];
  const int n0 = blockIdx.x * 128;

  __shared__ u16 As[128 * 64];
  __shared__ u16 Bs[128 * 64];

  const int t = threadIdx.x;
  const int lane = t & 63;
  const int wave = t >> 6;
  const int wm = (wave >> 1) * 64;
  const int wn = (wave & 1) * 64;
  const int r32 = lane & 31;
  const int half = lane >> 5;

  const int drow = t >> 3;
  const int dpos = t & 7;
  const u16* srcA[4];
  const u16* srcB[4];
  const u16* bbase = Wd + ((size_t)e * DD + n0) * DD;
#pragma unroll
  for (int i = 0; i < 4; i++) {
    const int row = drow + i * 32;
    int r = off + m0 + row; if (r > TK2 - 1) r = TK2 - 1;
    const int ka = (dpos ^ (row & 7)) * 8;
    srcA[i] = H + (size_t)r * DD + ka;
    srcB[i] = bbase + (size_t)row * DD + ka;
  }

  floatx16 acc[2][2];
#pragma unroll
  for (int i = 0; i < 2; i++)
#pragma unroll
    for (int j = 0; j < 2; j++)
      acc[i][j] = (floatx16)(0.f);

#pragma unroll 1
  for (int k0 = 0; k0 < DD; k0 += 64) {
    __syncthreads();
#pragma unroll
    for (int i = 0; i < 4; i++) {
      GLOAD_LDS16(srcA[i] + k0, &As[t * 8 + i * 2048]);
      GLOAD_LDS16(srcB[i] + k0, &Bs[t * 8 + i * 2048]);
    }
    __syncthreads();
#pragma unroll
    for (int s = 0; s < 4; s++) {
      const int kc = ((2 * s + half) ^ (r32 & 7)) * 8;
      short8 a[2], b[2];
#pragma unroll
      for (int i = 0; i < 2; i++)
        a[i] = *(const short8*)&As[(wm + i * 32 + r32) * 64 + kc];
#pragma unroll
      for (int j = 0; j < 2; j++)
        b[j] = *(const short8*)&Bs[(wn + j * 32 + r32) * 64 + kc];
#pragma unroll
      for (int i = 0; i < 2; i++)
#pragma unroll
        for (int j = 0; j < 2; j++)
          acc[i][j] = __builtin_amdgcn_mfma_f32_32x32x16_bf16(a[i], b[j], acc[i][j], 0, 0, 0);
    }
  }

#pragma unroll
  for (int i = 0; i < 2; i++) {
#pragma unroll
    for (int reg = 0; reg < 16; reg++) {
      const int m = m0 + wm + i * 32 + (reg & 3) + 8 * (reg >> 2) + 4 * half;
      if (m < cnt) {
        u16* yrow = Y + (size_t)(off + m) * DD + n0 + wn + r32;
#pragma unroll
        for (int j = 0; j < 2; j++)
          yrow[j * 32] = f2bf(acc[i][j][reg]);
      }
    }
  }
}

// ---------------- combine: out[t] = w0*Y[s0] + w1*Y[s1] ----------------
__global__ __launch_bounds__(256) void combine_kernel(
    const u16* __restrict__ Y, const int2* __restrict__ slots,
    const float2* __restrict__ wts, float* __restrict__ out, int T) {
  const int wave = threadIdx.x >> 6;
  const int lane = threadIdx.x & 63;
  const int t = blockIdx.x * 4 + wave;
  if (t >= T) return;
  const int2 s = slots[t];
  const float2 w = wts[t];
  const uint4* y0 = (const uint4*)(Y + (size_t)s.x * DD);
  const uint4* y1 = (const uint4*)(Y + (size_t)s.y * DD);
  float4* o = (float4*)(out + (size_t)t * DD);
#pragma unroll
  for (int c = 0; c < 2; c++) {
    const int idx = lane + c * 64;          // 128 uint4 per row (8 bf16 each)
    const uint4 a = y0[idx];
    const uint4 b = y1[idx];
    const u32 au[4] = {a.x, a.y, a.z, a.w};
    const u32 bu[4] = {b.x, b.y, b.z, b.w};
    float4 r[2];
#pragma unroll
    for (int q = 0; q < 4; q++) {
      const float2 fa = bf2f2(au[q]);
      const float2 fb = bf2f2(bu[q]);
      ((float*)r)[q * 2]     = w.x * fa.x + w.y * fb.x;
      ((float*)r)[q * 2 + 1] = w.x * fa.y + w.y * fb.y;
    }
    o[idx * 2]     = r[0];
    o[idx * 2 + 1] = r[1];
  }
}

extern "C" void kernel_launch(void* const* d_in, const int* in_sizes, int n_in,
                              void* d_out, int out_size, void* d_ws, size_t ws_size,
                              hipStream_t stream) {
  const float* x  = (const float*)d_in[0];
  const float* rw = (const float*)d_in[1];
  const float* rb = (const float*)d_in[2];
  const float* wg = (const float*)d_in[3];
  const float* wu = (const float*)d_in[4];
  const float* wd = (const float*)d_in[5];
  float* out = (float*)d_out;
  const int T = in_sizes[0] / DD;       // 16384
  const int TK2 = 2 * T;

  // workspace carve. Y (64MB) aliases [Wgu(32MB) xbf(32MB)], dead after gateup.
  char* p = (char*)d_ws;
  int* ctrl = (int*)p; p += 256;        // [0..7]=counts [8..15]=cursors [16..23]=offsets
  int2* experts = (int2*)p;  p += (size_t)T * 8;
  float2* wtsp  = (float2*)p; p += (size_t)T * 8;
  int* tok_id   = (int*)p;   p += (size_t)TK2 * 4;
  int2* slots   = (int2*)p;  p += (size_t)T * 8;
  u16* Wd       = (u16*)p;   p += (size_t)NE * DD * DD * 2;
  u16* H        = (u16*)p;   p += (size_t)TK2 * DD * 2;
  u16* Wgu      = (u16*)p;   // 32 MB
  u16* xbf      = (u16*)(p + (size_t)NE * 2048 * DD * 2);  // 32 MB
  u16* Y        = (u16*)p;   // 64 MB, aliases Wgu+xbf
  p += (size_t)TK2 * DD * 2;
  if ((size_t)(p - (char*)d_ws) > ws_size) return;  // insufficient scratch -> visible failure

  hipMemsetAsync(ctrl, 0, 256, stream);

  router_kernel<<<T / 4, 256, 0, stream>>>(x, rw, rb, experts, wtsp, xbf, ctrl, T);
  scatter_kernel<<<T / 256, 256, 0, stream>>>(experts, ctrl, ctrl + 8, tok_id, slots, T);
  offsets_kernel<<<1, 1, 0, stream>>>(ctrl, ctrl + 16);
  convert_kernel<<<dim3(16, 16, 24), 256, 0, stream>>>(wg, wu, wd, Wgu, Wd);
  gateup_kernel<<<dim3(16, (T + 127) / 128, NE), 256, 0, stream>>>(
      xbf, Wgu, tok_id, ctrl + 16, ctrl, H);
  down_kernel<<<dim3(8, (T + 127) / 128, NE), 256, 0, stream>>>(
      H, Wd, ctrl, ctrl + 16, Y, TK2);
  combine_kernel<<<T / 4, 256, 0, stream>>>(Y, slots, wtsp, out, T);
}